// Round 1
// baseline (379.697 us; speedup 1.0000x reference)
//
#include <hip/hip_runtime.h>

#define POOL 7
#define HH 100
#define WW 100
#define CC 512

__global__ __launch_bounds__(128) void roi_pool_kernel(
    const float* __restrict__ x, const int* __restrict__ rois,
    float* __restrict__ out, int R)
{
    const int cell = blockIdx.x;          // 0..48 : py*7+px
    const int px = cell % POOL;
    const int py = cell / POOL;
    const int r  = blockIdx.y;
    const int b  = blockIdx.z;

    // roi = (x1, y1, w, h)
    const int4 roi = ((const int4*)rois)[r];
    const int rx1 = roi.x, ry1 = roi.y, rw = roi.z, rh = roi.w;

    // y axis coords (match numpy fp32 order: (i+0.5)*(sz/7)-0.5, clip, floor)
    float szy = (float)rh;
    float vy = ((float)py + 0.5f) * (szy / (float)POOL) - 0.5f;
    vy = fminf(fmaxf(vy, 0.0f), szy - 1.0f);
    int   ylo = (int)floorf(vy);
    float fy  = vy - (float)ylo;
    int   yhi = min(ylo + 1, rh - 1);
    int gy0 = ry1 + ylo, gy1 = ry1 + yhi;

    // x axis coords
    float szx = (float)rw;
    float vx = ((float)px + 0.5f) * (szx / (float)POOL) - 0.5f;
    vx = fminf(fmaxf(vx, 0.0f), szx - 1.0f);
    int   xlo = (int)floorf(vx);
    float fx  = vx - (float)xlo;
    int   xhi = min(xlo + 1, rw - 1);
    int gx0 = rx1 + xlo, gx1 = rx1 + xhi;

    const size_t base = (size_t)b * HH * WW * CC;
    const float4* ptl = (const float4*)(x + base + ((size_t)gy0 * WW + gx0) * CC);
    const float4* ptr_ = (const float4*)(x + base + ((size_t)gy0 * WW + gx1) * CC);
    const float4* pbl = (const float4*)(x + base + ((size_t)gy1 * WW + gx0) * CC);
    const float4* pbr = (const float4*)(x + base + ((size_t)gy1 * WW + gx1) * CC);

    float4* po = (float4*)(out + ((((size_t)b * R + r) * POOL + py) * POOL + px) * CC);

    const int c = threadIdx.x;  // 0..127, 4 channels each (512 total)
    float4 tl = ptl[c], tr = ptr_[c], bl = pbl[c], br = pbr[c];

    float4 o;
    {
        float top = tl.x + (tr.x - tl.x) * fx;
        float bot = bl.x + (br.x - bl.x) * fx;
        o.x = top + (bot - top) * fy;
    }
    {
        float top = tl.y + (tr.y - tl.y) * fx;
        float bot = bl.y + (br.y - bl.y) * fx;
        o.y = top + (bot - top) * fy;
    }
    {
        float top = tl.z + (tr.z - tl.z) * fx;
        float bot = bl.z + (br.z - bl.z) * fx;
        o.z = top + (bot - top) * fy;
    }
    {
        float top = tl.w + (tr.w - tl.w) * fx;
        float bot = bl.w + (br.w - bl.w) * fx;
        o.w = top + (bot - top) * fy;
    }
    po[c] = o;
}

extern "C" void kernel_launch(void* const* d_in, const int* in_sizes, int n_in,
                              void* d_out, int out_size, void* d_ws, size_t ws_size,
                              hipStream_t stream) {
    const float* x   = (const float*)d_in[0];
    const int* rois  = (const int*)d_in[1];
    float* out       = (float*)d_out;

    const int R = in_sizes[1] / 4;                     // 300
    const int B = in_sizes[0] / (HH * WW * CC);        // 8

    dim3 grid(POOL * POOL, R, B);
    dim3 block(128);
    roi_pool_kernel<<<grid, block, 0, stream>>>(x, rois, out, R);
}

// Round 3
// 370.467 us; speedup vs baseline: 1.0249x; 1.0249x over previous
//
#include <hip/hip_runtime.h>

#define POOL 7
#define HH 100
#define WW 100
#define CC 512

typedef float vfloat4 __attribute__((ext_vector_type(4)));

__global__ __launch_bounds__(128) void roi_pool_kernel(
    const float* __restrict__ x, const int* __restrict__ rois,
    float* __restrict__ out, int R)
{
    const int cell = blockIdx.x;          // 0..48 : py*7+px
    const int px = cell % POOL;
    const int py = cell / POOL;
    const int r  = blockIdx.y;
    const int b  = blockIdx.z;

    // roi = (x1, y1, w, h)
    const int4 roi = ((const int4*)rois)[r];
    const int rx1 = roi.x, ry1 = roi.y, rw = roi.z, rh = roi.w;

    // y axis coords (match numpy fp32 order: (i+0.5)*(sz/7)-0.5, clip, floor)
    float szy = (float)rh;
    float vy = ((float)py + 0.5f) * (szy / (float)POOL) - 0.5f;
    vy = fminf(fmaxf(vy, 0.0f), szy - 1.0f);
    int   ylo = (int)floorf(vy);
    float fy  = vy - (float)ylo;
    int   yhi = min(ylo + 1, rh - 1);
    int gy0 = ry1 + ylo, gy1 = ry1 + yhi;

    // x axis coords
    float szx = (float)rw;
    float vx = ((float)px + 0.5f) * (szx / (float)POOL) - 0.5f;
    vx = fminf(fmaxf(vx, 0.0f), szx - 1.0f);
    int   xlo = (int)floorf(vx);
    float fx  = vx - (float)xlo;
    int   xhi = min(xlo + 1, rw - 1);
    int gx0 = rx1 + xlo, gx1 = rx1 + xhi;

    const bool need_x = (fx != 0.0f);   // block-uniform → no divergence
    const bool need_y = (fy != 0.0f);

    const size_t base = (size_t)b * HH * WW * CC;
    const vfloat4* ptl  = (const vfloat4*)(x + base + ((size_t)gy0 * WW + gx0) * CC);
    const vfloat4* ptr_ = (const vfloat4*)(x + base + ((size_t)gy0 * WW + gx1) * CC);
    const vfloat4* pbl  = (const vfloat4*)(x + base + ((size_t)gy1 * WW + gx0) * CC);
    const vfloat4* pbr  = (const vfloat4*)(x + base + ((size_t)gy1 * WW + gx1) * CC);

    vfloat4* po = (vfloat4*)(out + ((((size_t)b * R + r) * POOL + py) * POOL + px) * CC);

    const int c = threadIdx.x;  // 0..127, 4 channels each (512 total)
    vfloat4 tl = ptl[c];
    vfloat4 tr = tl, bl = tl, br = tl;
    if (need_x) tr = ptr_[c];
    if (need_y) {
        bl = pbl[c];
        br = bl;
        if (need_x) br = pbr[c];
    }

    vfloat4 top = tl + (tr - tl) * fx;
    vfloat4 bot = bl + (br - bl) * fx;
    vfloat4 o   = top + (bot - top) * fy;

    // output is never re-read: nontemporal store keeps L2 free for input reuse
    __builtin_nontemporal_store(o, po + c);
}

extern "C" void kernel_launch(void* const* d_in, const int* in_sizes, int n_in,
                              void* d_out, int out_size, void* d_ws, size_t ws_size,
                              hipStream_t stream) {
    const float* x   = (const float*)d_in[0];
    const int* rois  = (const int*)d_in[1];
    float* out       = (float*)d_out;

    const int R = in_sizes[1] / 4;                     // 300
    const int B = in_sizes[0] / (HH * WW * CC);        // 8

    dim3 grid(POOL * POOL, R, B);
    dim3 block(128);
    roi_pool_kernel<<<grid, block, 0, stream>>>(x, rois, out, R);
}